// Round 2
// baseline (1058.256 us; speedup 1.0000x reference)
//
#include <hip/hip_runtime.h>

typedef unsigned short u16;
typedef unsigned int   u32;
typedef __attribute__((ext_vector_type(8))) __bf16 bf16x8;
typedef __attribute__((ext_vector_type(4))) float   f32x4;

// ---------------- dims ----------------
#define NT   16384      // tokens = 4*4096
#define DD   1024
#define FFD  4096

// ---------------- ws layout (bytes), total ~152 MB ----------------
#define SREG  ((size_t)33554432)            // 32MB = 16384*1024*2
#define S1O   ((size_t)0)
#define S2O   (SREG)
#define S3O   (2*SREG)
#define S4O   (3*SREG)
#define O_WQ  (4*SREG)                      // 134,217,728
#define O_WK  (O_WQ + (size_t)2097152)
#define O_W1  (O_WK + (size_t)2097152)
#define O_W2  (O_W1 + (size_t)8388608)
#define O_FWD (O_W2 + (size_t)8388608)
#define O_INV (O_FWD + (size_t)2097152)
#define O_SF  (O_INV + (size_t)2097152)
// end = O_SF + 16384 = 159,399,936 bytes

// ---------------- helpers ----------------
__device__ __forceinline__ float b2f(u16 h) {
    u32 u = ((u32)h) << 16;
    return __uint_as_float(u);
}
__device__ __forceinline__ u16 f2b(float f) {  // RNE
    u32 u = __float_as_uint(f);
    u32 r = (u + 0x7FFFu + ((u >> 16) & 1u)) >> 16;
    return (u16)r;
}

__device__ __forceinline__ void ld16(const u16* g, u16* l) {
    __builtin_amdgcn_global_load_lds(
        (const __attribute__((address_space(1))) void*)g,
        (__attribute__((address_space(3))) void*)l, 16, 0, 0);
}

__device__ __forceinline__ void block_red2(float& a, float& b, float* red, int tid) {
#pragma unroll
    for (int off = 32; off; off >>= 1) {
        a += __shfl_down(a, off, 64);
        b += __shfl_down(b, off, 64);
    }
    int w = tid >> 6;
    if ((tid & 63) == 0) { red[w] = a; red[4 + w] = b; }
    __syncthreads();
    a = red[0] + red[1] + red[2] + red[3];
    b = red[4] + red[5] + red[6] + red[7];
}

// ---------------- small utility kernels ----------------
__global__ void zero_sf_k(float* __restrict__ Sf) {
    int i = blockIdx.x * 256 + threadIdx.x;
    if (i < 4096) Sf[i] = 0.f;
}

__global__ void cast_f32_bf16_k(const float* __restrict__ s, u16* __restrict__ d, int n4) {
    int i = blockIdx.x * 256 + threadIdx.x;
    if (i < n4) {
        float4 v = ((const float4*)s)[i];
        ushort4 o;
        o.x = f2b(v.x); o.y = f2b(v.y); o.z = f2b(v.z); o.w = f2b(v.w);
        ((ushort4*)d)[i] = o;
    }
}

// ---------------- packed-spectrum DFT matrices (bf16) ----------------
// Packed layout (1024 cols): col0 = Re F_0; odd n -> Re F_{(n+1)/2}; even n>0 -> Im F_{n/2};
// col 1023 (odd) -> Re F_512.  numpy rfft: F_f = sum_k v_k e^{-2pi i f k /1024}.
// Fwd[n,k]: Re rows -> cos(2pi f k/1024), Im rows -> -sin(2pi f k/1024).
__global__ void gen_fwd_k(u16* __restrict__ Fwd) {
    int idx = blockIdx.x * 256 + threadIdx.x;   // 1024*1024
    int n = idx >> 10, k = idx & 1023;
    int f  = (n == 0) ? 0 : ((n & 1) ? ((n + 1) >> 1) : (n >> 1));
    bool re = (n == 0) || (n & 1);
    int r = (f * k) & 1023;
    float ang = (float)r * 6.1359233e-3f;   // 2*pi/1024
    float v = re ? __cosf(ang) : -__sinf(ang);
    Fwd[idx] = f2b(v);
}
// irfft: v_d = (1/1024)[F_0 + (-1)^d Re F_512 + 2*sum_{f=1}^{511}(Re F_f cos - Im F_f sin)]
// Inv[d,n]: Re cols -> +c*cos, Im cols -> -c*sin; c = 1/1024 for f in {0,512} else 2/1024.
__global__ void gen_inv_k(u16* __restrict__ Inv) {
    int idx = blockIdx.x * 256 + threadIdx.x;   // 1024*1024
    int d = idx >> 10, n = idx & 1023;
    int f  = (n == 0) ? 0 : ((n & 1) ? ((n + 1) >> 1) : (n >> 1));
    bool re = (n == 0) || (n & 1);
    int r = (f * d) & 1023;
    float ang = (float)r * 6.1359233e-3f;
    float c = (f == 0 || f == 512) ? (1.0f / 1024.0f) : (2.0f / 1024.0f);
    float v = re ? c * __cosf(ang) : -c * __sinf(ang);
    Inv[idx] = f2b(v);
}

// ---------------- GEMM: C[m,n] = sum_k A[m,k]*B[n,k]  (m97 structure) ----------------
#define BM 128
#define BN 128
#define BK 64
#define EPI_BF16            0  // bf16 store
#define EPI_BIAS_BF16       1  // bf16 store, + bias[n]
#define EPI_BIAS_RELU_BF16  2  // bf16 store, + bias[n], relu
#define EPI_BIAS_ADDB_F32   3  // f32 store,  + bias[n] + bf16 residual addp16[off]
#define EPI_ADD_F32         4  // f32 store,  + existing f32 Cout[off]

template <int EPI>
__global__ __launch_bounds__(256, 2) void gemm_bt_k(
    const u16* __restrict__ A, const u16* __restrict__ B, void* __restrict__ Cout,
    const float* __restrict__ bias, const u16* __restrict__ addp16,
    int K, int lda, int ldb, int ldc)
{
    __shared__ __align__(16) u16 As[BM * BK];
    __shared__ __align__(16) u16 Bs[BN * BK];
    const int tid = threadIdx.x;
    const int m0 = blockIdx.y * BM, n0 = blockIdx.x * BN;
    const int w = tid >> 6, l = tid & 63;
    const int wm = (w >> 1) << 6, wn = (w & 1) << 6;
    const int tm = l & 15, quad = l >> 4;

    f32x4 acc[4][4] = {};

    const int sr = tid >> 3;
    const int sc = (tid & 7) << 3;
    const u16* Ag = A + (size_t)(m0 + sr) * lda + sc;
    const u16* Bg = B + (size_t)(n0 + sr) * ldb + sc;
    u16* Asl = As + tid * 8;
    u16* Bsl = Bs + tid * 8;
    const size_t a32 = (size_t)32 * lda, b32 = (size_t)32 * ldb;

    for (int k0 = 0; k0 < K; k0 += BK) {
#pragma unroll
        for (int i = 0; i < 4; ++i) {
            ld16(Ag + (size_t)i * a32 + k0, Asl + i * 2048);
            ld16(Bg + (size_t)i * b32 + k0, Bsl + i * 2048);
        }
        __syncthreads();
#pragma unroll
        for (int kk = 0; kk < BK; kk += 32) {
            bf16x8 af[4], bfr[4];
#pragma unroll
            for (int i = 0; i < 4; ++i)
                af[i] = *(const bf16x8*)(const void*)(As + (wm + i * 16 + tm) * BK + kk + quad * 8);
#pragma unroll
            for (int j = 0; j < 4; ++j)
                bfr[j] = *(const bf16x8*)(const void*)(Bs + (wn + j * 16 + tm) * BK + kk + quad * 8);
#pragma unroll
            for (int i = 0; i < 4; ++i)
#pragma unroll
                for (int j = 0; j < 4; ++j)
                    acc[i][j] = __builtin_amdgcn_mfma_f32_16x16x32_bf16(af[i], bfr[j], acc[i][j], 0, 0, 0);
        }
        __syncthreads();
    }

    // C/D layout: col=lane&15, row=quad*4+reg (m89/m91-verified)
#pragma unroll
    for (int i = 0; i < 4; ++i) {
        const int gmb = m0 + wm + i * 16 + quad * 4;
#pragma unroll
        for (int j = 0; j < 4; ++j) {
            const int gn = n0 + wn + j * 16 + tm;
            float bv = 0.f;
            if (EPI == EPI_BIAS_BF16 || EPI == EPI_BIAS_RELU_BF16 || EPI == EPI_BIAS_ADDB_F32)
                bv = bias[gn];
#pragma unroll
            for (int r = 0; r < 4; ++r) {
                size_t off = (size_t)(gmb + r) * ldc + gn;
                float v = acc[i][j][r] + bv;
                if (EPI == EPI_BIAS_ADDB_F32) v += b2f(addp16[off]);
                if (EPI == EPI_ADD_F32)       v += ((const float*)Cout)[off];
                if (EPI == EPI_BIAS_RELU_BF16) v = fmaxf(v, 0.f);
                if (EPI == EPI_BF16 || EPI == EPI_BIAS_BF16 || EPI == EPI_BIAS_RELU_BF16)
                    ((u16*)Cout)[off] = f2b(v);
                else
                    ((float*)Cout)[off] = v;
            }
        }
    }
}

// ---------------- LayerNorm bf16 -> bf16 (may be in-place) ----------------
__global__ void ln_bf16_k(const u16* __restrict__ src, u16* __restrict__ dst,
                          const float* __restrict__ g, const float* __restrict__ be) {
    __shared__ float red[8];
    const int t = blockIdx.x, tid = threadIdx.x;
    ushort4 h = ((const ushort4*)(src + (size_t)t * DD))[tid];
    float4 v = { b2f(h.x), b2f(h.y), b2f(h.z), b2f(h.w) };
    float s  = v.x + v.y + v.z + v.w;
    float ss = v.x * v.x + v.y * v.y + v.z * v.z + v.w * v.w;
    block_red2(s, ss, red, tid);
    float mean = s * (1.f / 1024.f);
    float inv  = 1.0f / sqrtf(ss * (1.f / 1024.f) - mean * mean + 1e-5f);
    float4 gv = ((const float4*)g)[tid];
    float4 bv = ((const float4*)be)[tid];
    ushort4 o;
    o.x = f2b((v.x - mean) * inv * gv.x + bv.x);
    o.y = f2b((v.y - mean) * inv * gv.y + bv.y);
    o.z = f2b((v.z - mean) * inv * gv.z + bv.z);
    o.w = f2b((v.w - mean) * inv * gv.w + bv.w);
    ((ushort4*)(dst + (size_t)t * DD))[tid] = o;
}

// ---------------- final LN in place on d_out (f32) ----------------
__global__ void ln_out_k(float* __restrict__ io, const float* __restrict__ g,
                         const float* __restrict__ be) {
    __shared__ float red[8];
    const int t = blockIdx.x, tid = threadIdx.x;
    float4 v = ((const float4*)(io + (size_t)t * DD))[tid];
    float s  = v.x + v.y + v.z + v.w;
    float ss = v.x * v.x + v.y * v.y + v.z * v.z + v.w * v.w;
    block_red2(s, ss, red, tid);
    float mean = s * (1.f / 1024.f);
    float inv  = 1.0f / sqrtf(ss * (1.f / 1024.f) - mean * mean + 1e-5f);
    float4 gv = ((const float4*)g)[tid];
    float4 bv = ((const float4*)be)[tid];
    float4 o;
    o.x = (v.x - mean) * inv * gv.x + bv.x;
    o.y = (v.y - mean) * inv * gv.y + bv.y;
    o.z = (v.z - mean) * inv * gv.z + bv.z;
    o.w = (v.w - mean) * inv * gv.w + bv.w;
    ((float4*)(io + (size_t)t * DD))[tid] = o;
}

// ---------------- pw1: Sf[b] += Kf .* Xf  (packed spectra) ----------------
// thread tid handles complex bins f=tid+1 and f=tid+257 (cols 2f-1,2f);
// tid==255's second bin is f=512 -> real-only col 1023; tid==0 also does f=0 col 0.
#define PW1_TOK 16
__global__ void pw1_k(const u16* __restrict__ FTx, const u16* __restrict__ FTk,
                      float* __restrict__ Sf) {
    const int tid = threadIdx.x;
    const int t0 = blockIdx.x * PW1_TOK;
    const int b = t0 >> 12;
    float a0 = 0.f;                       // f=0 (tid 0 only)
    float ar1 = 0.f, ai1 = 0.f;           // f = tid+1
    float ar2 = 0.f, ai2 = 0.f;           // f = tid+257 (or f=512 real for tid 255)
    const int f1 = tid + 1, f2 = tid + 257;
    for (int it = 0; it < PW1_TOK; ++it) {
        const size_t ro = (size_t)(t0 + it) * DD;
        const u16* rx = FTx + ro;
        const u16* rk = FTk + ro;
        if (tid == 0) a0 += b2f(rk[0]) * b2f(rx[0]);
        {
            float xr = b2f(rx[2 * f1 - 1]), xi = b2f(rx[2 * f1]);
            float kr = b2f(rk[2 * f1 - 1]), ki = b2f(rk[2 * f1]);
            ar1 += kr * xr - ki * xi;
            ai1 += kr * xi + ki * xr;
        }
        if (f2 < 512) {
            float xr = b2f(rx[2 * f2 - 1]), xi = b2f(rx[2 * f2]);
            float kr = b2f(rk[2 * f2 - 1]), ki = b2f(rk[2 * f2]);
            ar2 += kr * xr - ki * xi;
            ai2 += kr * xi + ki * xr;
        } else {
            ar2 += b2f(rk[1023]) * b2f(rx[1023]);
        }
    }
    float* sb = Sf + (size_t)b * DD;
    if (tid == 0) atomicAdd(&sb[0], a0);
    atomicAdd(&sb[2 * f1 - 1], ar1);
    atomicAdd(&sb[2 * f1],     ai1);
    if (f2 < 512) {
        atomicAdd(&sb[2 * f2 - 1], ar2);
        atomicAdd(&sb[2 * f2],     ai2);
    } else {
        atomicAdd(&sb[1023], ar2);
    }
}

// ---------------- pw2: G = Xf + Kf.*Xf + Sf.*conj(Qf), written in-place over FTx --------
__global__ void pw2_k(u16* __restrict__ FTx, const u16* __restrict__ FTk,
                      const u16* __restrict__ FTq, const float* __restrict__ Sf) {
    const int t = blockIdx.x, tid = threadIdx.x;
    const int b = t >> 12;
    const size_t ro = (size_t)t * DD;
    u16* rx = FTx + ro;
    const u16* rk = FTk + ro;
    const u16* rq = FTq + ro;
    const float* sb = Sf + (size_t)b * DD;
    const int f1 = tid + 1, f2 = tid + 257;
    if (tid == 0) {
        float x = b2f(rx[0]), k = b2f(rk[0]), q = b2f(rq[0]);
        rx[0] = f2b(x + k * x + sb[0] * q);
    }
    {
        float xr = b2f(rx[2 * f1 - 1]), xi = b2f(rx[2 * f1]);
        float kr = b2f(rk[2 * f1 - 1]), ki = b2f(rk[2 * f1]);
        float qr = b2f(rq[2 * f1 - 1]), qi = b2f(rq[2 * f1]);
        float sr = sb[2 * f1 - 1], si = sb[2 * f1];
        rx[2 * f1 - 1] = f2b(xr + (kr * xr - ki * xi) + (sr * qr + si * qi));
        rx[2 * f1]     = f2b(xi + (kr * xi + ki * xr) + (si * qr - sr * qi));
    }
    if (f2 < 512) {
        float xr = b2f(rx[2 * f2 - 1]), xi = b2f(rx[2 * f2]);
        float kr = b2f(rk[2 * f2 - 1]), ki = b2f(rk[2 * f2]);
        float qr = b2f(rq[2 * f2 - 1]), qi = b2f(rq[2 * f2]);
        float sr = sb[2 * f2 - 1], si = sb[2 * f2];
        rx[2 * f2 - 1] = f2b(xr + (kr * xr - ki * xi) + (sr * qr + si * qi));
        rx[2 * f2]     = f2b(xi + (kr * xi + ki * xr) + (si * qr - sr * qi));
    } else {
        float x = b2f(rx[1023]), k = b2f(rk[1023]), q = b2f(rq[1023]);
        rx[1023] = f2b(x + k * x + sb[1023] * q);
    }
}

// ---------------- launch ----------------
extern "C" void kernel_launch(void* const* d_in, const int* in_sizes, int n_in,
                              void* d_out, int out_size, void* d_ws, size_t ws_size,
                              hipStream_t stream) {
    const float* x     = (const float*)d_in[0];
    const float* Wq    = (const float*)d_in[1];
    const float* bq    = (const float*)d_in[2];
    const float* gq    = (const float*)d_in[3];
    const float* betaq = (const float*)d_in[4];
    const float* Wk    = (const float*)d_in[5];
    const float* bk    = (const float*)d_in[6];
    const float* gk    = (const float*)d_in[7];
    const float* betak = (const float*)d_in[8];
    const float* g0    = (const float*)d_in[9];
    const float* beta0 = (const float*)d_in[10];
    const float* W1    = (const float*)d_in[11];
    const float* b1    = (const float*)d_in[12];
    const float* W2    = (const float*)d_in[13];
    const float* b2    = (const float*)d_in[14];
    const float* g1    = (const float*)d_in[15];
    const float* beta1 = (const float*)d_in[16];

    char* ws = (char*)d_ws;
    u16* S1 = (u16*)(ws + S1O);   // xb16 -> FTk -> x1b
    u16* S2 = (u16*)(ws + S2O);   // qb -> T
    u16* S3 = (u16*)(ws + S3O);   // kb -> FTq -> H(lo half)
    u16* S4 = (u16*)(ws + S4O);   // FTx -> G -> H(hi half)
    u16* wq16 = (u16*)(ws + O_WQ);
    u16* wk16 = (u16*)(ws + O_WK);
    u16* w116 = (u16*)(ws + O_W1);
    u16* w216 = (u16*)(ws + O_W2);
    u16* fwdP = (u16*)(ws + O_FWD);
    u16* invP = (u16*)(ws + O_INV);
    float* Sf = (float*)(ws + O_SF);
    float* out = (float*)d_out;

    // consts
    zero_sf_k<<<16, 256, 0, stream>>>(Sf);
    cast_f32_bf16_k<<<16384, 256, 0, stream>>>(x, S1, 4194304);
    cast_f32_bf16_k<<<1024, 256, 0, stream>>>(Wq, wq16, 262144);
    cast_f32_bf16_k<<<1024, 256, 0, stream>>>(Wk, wk16, 262144);
    cast_f32_bf16_k<<<4096, 256, 0, stream>>>(W1, w116, 1048576);
    cast_f32_bf16_k<<<4096, 256, 0, stream>>>(W2, w216, 1048576);
    gen_fwd_k<<<4096, 256, 0, stream>>>(fwdP);
    gen_inv_k<<<4096, 256, 0, stream>>>(invP);

    // projections (bias in epilogue, bf16 out), then LN in-place
    gemm_bt_k<EPI_BIAS_BF16><<<dim3(8, 128), 256, 0, stream>>>(S1, wq16, S2, bq, nullptr, 1024, 1024, 1024, 1024);
    gemm_bt_k<EPI_BIAS_BF16><<<dim3(8, 128), 256, 0, stream>>>(S1, wk16, S3, bk, nullptr, 1024, 1024, 1024, 1024);
    ln_bf16_k<<<NT, 256, 0, stream>>>(S2, S2, gq, betaq);
    ln_bf16_k<<<NT, 256, 0, stream>>>(S3, S3, gk, betak);

    // forward DFTs (packed spectra)
    gemm_bt_k<EPI_BF16><<<dim3(8, 128), 256, 0, stream>>>(S1, fwdP, S4, nullptr, nullptr, 1024, 1024, 1024, 1024); // FTx
    gemm_bt_k<EPI_BF16><<<dim3(8, 128), 256, 0, stream>>>(S3, fwdP, S1, nullptr, nullptr, 1024, 1024, 1024, 1024); // FTk
    gemm_bt_k<EPI_BF16><<<dim3(8, 128), 256, 0, stream>>>(S2, fwdP, S3, nullptr, nullptr, 1024, 1024, 1024, 1024); // FTq

    // freq-domain pointwise
    pw1_k<<<NT / PW1_TOK, 256, 0, stream>>>(S4, S1, Sf);
    pw2_k<<<NT, 256, 0, stream>>>(S4, S1, S3, Sf);   // G in-place over FTx (S4)

    // inverse DFT: T = G @ Inv^T (bf16)
    gemm_bt_k<EPI_BF16><<<dim3(8, 128), 256, 0, stream>>>(S4, invP, S2, nullptr, nullptr, 1024, 1024, 1024, 1024);

    // x1 = LN(T) -> bf16
    ln_bf16_k<<<NT, 256, 0, stream>>>(S2, S1, g0, beta0);

    // FFN in two F-chunks of 2048; H lives in S3..S4 (64MB)
    gemm_bt_k<EPI_BIAS_RELU_BF16><<<dim3(16, 128), 256, 0, stream>>>(S1, w116, S3, b1, nullptr, 1024, 1024, 1024, 2048);
    gemm_bt_k<EPI_BIAS_ADDB_F32><<<dim3(8, 128), 256, 0, stream>>>(S3, w216, out, b2, S1, 2048, 2048, 4096, 1024);
    gemm_bt_k<EPI_BIAS_RELU_BF16><<<dim3(16, 128), 256, 0, stream>>>(S1, w116 + (size_t)2048 * 1024, S3, b1 + 2048, nullptr, 1024, 1024, 1024, 2048);
    gemm_bt_k<EPI_ADD_F32><<<dim3(8, 128), 256, 0, stream>>>(S3, w216 + 2048, out, nullptr, nullptr, 2048, 2048, 4096, 1024);

    // final LN in place
    ln_out_k<<<NT, 256, 0, stream>>>(out, g1, beta1);

    (void)in_sizes; (void)n_in; (void)out_size; (void)ws_size;
}

// Round 3
// 991.324 us; speedup vs baseline: 1.0675x; 1.0675x over previous
//
#include <hip/hip_runtime.h>

typedef unsigned short u16;
typedef unsigned int   u32;
typedef __attribute__((ext_vector_type(8))) __bf16 bf16x8;
typedef __attribute__((ext_vector_type(4))) float   f32x4;

// ---------------- dims ----------------
#define NT   16384      // tokens = 4*4096
#define DD   1024
#define FFD  4096

// ---------------- ws layout (bytes), total ~152 MB ----------------
#define SREG  ((size_t)33554432)            // 32MB = 16384*1024*2
#define S1O   ((size_t)0)
#define S2O   (SREG)
#define S3O   (2*SREG)
#define S4O   (3*SREG)
#define O_WQ  (4*SREG)                      // 134,217,728
#define O_WK  (O_WQ + (size_t)2097152)
#define O_W1  (O_WK + (size_t)2097152)
#define O_W2  (O_W1 + (size_t)8388608)
#define O_FWD (O_W2 + (size_t)8388608)
#define O_INV (O_FWD + (size_t)2097152)
#define O_SF  (O_INV + (size_t)2097152)
// end = O_SF + 16384 = 159,399,936 bytes

// ---------------- helpers ----------------
__device__ __forceinline__ float b2f(u16 h) {
    u32 u = ((u32)h) << 16;
    return __uint_as_float(u);
}
__device__ __forceinline__ u16 f2b(float f) {  // RNE
    u32 u = __float_as_uint(f);
    u32 r = (u + 0x7FFFu + ((u >> 16) & 1u)) >> 16;
    return (u16)r;
}

__device__ __forceinline__ void ld16(const u16* g, u16* l) {
    __builtin_amdgcn_global_load_lds(
        (const __attribute__((address_space(1))) void*)g,
        (__attribute__((address_space(3))) void*)l, 16, 0, 0);
}

__device__ __forceinline__ void block_red2(float& a, float& b, float* red, int tid) {
#pragma unroll
    for (int off = 32; off; off >>= 1) {
        a += __shfl_down(a, off, 64);
        b += __shfl_down(b, off, 64);
    }
    int w = tid >> 6;
    if ((tid & 63) == 0) { red[w] = a; red[4 + w] = b; }
    __syncthreads();
    a = red[0] + red[1] + red[2] + red[3];
    b = red[4] + red[5] + red[6] + red[7];
}

// ---------------- small utility kernels ----------------
__global__ void zero_sf_k(float* __restrict__ Sf) {
    int i = blockIdx.x * 256 + threadIdx.x;
    if (i < 4096) Sf[i] = 0.f;
}

__global__ void cast_f32_bf16_k(const float* __restrict__ s, u16* __restrict__ d, int n4) {
    int i = blockIdx.x * 256 + threadIdx.x;
    if (i < n4) {
        float4 v = ((const float4*)s)[i];
        ushort4 o;
        o.x = f2b(v.x); o.y = f2b(v.y); o.z = f2b(v.z); o.w = f2b(v.w);
        ((ushort4*)d)[i] = o;
    }
}

// ---------------- packed-spectrum DFT matrices (bf16) ----------------
// Packed layout (1024 cols): col0 = Re F_0; odd n -> Re F_{(n+1)/2}; even n>0 -> Im F_{n/2};
// col 1023 (odd) -> Re F_512.  numpy rfft: F_f = sum_k v_k e^{-2pi i f k /1024}.
__global__ void gen_fwd_k(u16* __restrict__ Fwd) {
    int idx = blockIdx.x * 256 + threadIdx.x;   // 1024*1024
    int n = idx >> 10, k = idx & 1023;
    int f  = (n == 0) ? 0 : ((n & 1) ? ((n + 1) >> 1) : (n >> 1));
    bool re = (n == 0) || (n & 1);
    int r = (f * k) & 1023;
    float ang = (float)r * 6.1359233e-3f;   // 2*pi/1024
    float v = re ? __cosf(ang) : -__sinf(ang);
    Fwd[idx] = f2b(v);
}
// irfft: v_d = (1/1024)[F_0 + (-1)^d Re F_512 + 2*sum_{f=1}^{511}(Re F_f cos - Im F_f sin)]
__global__ void gen_inv_k(u16* __restrict__ Inv) {
    int idx = blockIdx.x * 256 + threadIdx.x;   // 1024*1024
    int d = idx >> 10, n = idx & 1023;
    int f  = (n == 0) ? 0 : ((n & 1) ? ((n + 1) >> 1) : (n >> 1));
    bool re = (n == 0) || (n & 1);
    int r = (f * d) & 1023;
    float ang = (float)r * 6.1359233e-3f;
    float c = (f == 0 || f == 512) ? (1.0f / 1024.0f) : (2.0f / 1024.0f);
    float v = re ? c * __cosf(ang) : -c * __sinf(ang);
    Inv[idx] = f2b(v);
}

// ---------------- GEMM: C[m,n] = sum_k A[m,k]*B[n,k]  (m97 structure + XCD swizzle) ------
#define BM 128
#define BN 128
#define BK 64
#define EPI_BF16            0  // bf16 store
#define EPI_BIAS_BF16       1  // bf16 store, + bias[n]
#define EPI_BIAS_RELU_BF16  2  // bf16 store, + bias[n], relu
#define EPI_BIAS_ADDB_F32   3  // f32 store,  + bias[n] + bf16 residual addp16[off]
#define EPI_ADD_F32         4  // f32 store,  + existing f32 Cout[off]

template <int EPI>
__global__ __launch_bounds__(256, 2) void gemm_bt_k(
    const u16* __restrict__ A, const u16* __restrict__ B, void* __restrict__ Cout,
    const float* __restrict__ bias, const u16* __restrict__ addp16,
    int K, int lda, int ldb, int ldc)
{
    __shared__ __align__(16) u16 As[BM * BK];
    __shared__ __align__(16) u16 Bs[BN * BK];
    const int tid = threadIdx.x;

    // XCD-aware swizzle: HW maps block id round-robin to XCDs (id%8). Remap so
    // blocks with id%8==c (one XCD) cover a CONTIGUOUS m-band x all n-tiles:
    // per-XCD A-operand footprint drops 8x, A-tile reused by consecutive blocks.
    int m0, n0;
    {
        const int id = blockIdx.y * gridDim.x + blockIdx.x;
        const int nb = gridDim.x * gridDim.y;
        if ((nb & 7) == 0) {
            const int per = nb >> 3;
            const int t = (id & 7) * per + (id >> 3);
            n0 = (t % gridDim.x) * BN;
            m0 = (t / gridDim.x) * BM;
        } else {
            n0 = blockIdx.x * BN;
            m0 = blockIdx.y * BM;
        }
    }

    const int w = tid >> 6, l = tid & 63;
    const int wm = (w >> 1) << 6, wn = (w & 1) << 6;
    const int tm = l & 15, quad = l >> 4;

    f32x4 acc[4][4] = {};

    const int sr = tid >> 3;
    const int sc = (tid & 7) << 3;
    const u16* Ag = A + (size_t)(m0 + sr) * lda + sc;
    const u16* Bg = B + (size_t)(n0 + sr) * ldb + sc;
    u16* Asl = As + tid * 8;
    u16* Bsl = Bs + tid * 8;
    const size_t a32 = (size_t)32 * lda, b32 = (size_t)32 * ldb;

    for (int k0 = 0; k0 < K; k0 += BK) {
#pragma unroll
        for (int i = 0; i < 4; ++i) {
            ld16(Ag + (size_t)i * a32 + k0, Asl + i * 2048);
            ld16(Bg + (size_t)i * b32 + k0, Bsl + i * 2048);
        }
        __syncthreads();
#pragma unroll
        for (int kk = 0; kk < BK; kk += 32) {
            bf16x8 af[4], bfr[4];
#pragma unroll
            for (int i = 0; i < 4; ++i)
                af[i] = *(const bf16x8*)(const void*)(As + (wm + i * 16 + tm) * BK + kk + quad * 8);
#pragma unroll
            for (int j = 0; j < 4; ++j)
                bfr[j] = *(const bf16x8*)(const void*)(Bs + (wn + j * 16 + tm) * BK + kk + quad * 8);
#pragma unroll
            for (int i = 0; i < 4; ++i)
#pragma unroll
                for (int j = 0; j < 4; ++j)
                    acc[i][j] = __builtin_amdgcn_mfma_f32_16x16x32_bf16(af[i], bfr[j], acc[i][j], 0, 0, 0);
        }
        __syncthreads();
    }

    // C/D layout: col=lane&15, row=quad*4+reg (m89/m91-verified)
#pragma unroll
    for (int i = 0; i < 4; ++i) {
        const int gmb = m0 + wm + i * 16 + quad * 4;
#pragma unroll
        for (int j = 0; j < 4; ++j) {
            const int gn = n0 + wn + j * 16 + tm;
            float bv = 0.f;
            if (EPI == EPI_BIAS_BF16 || EPI == EPI_BIAS_RELU_BF16 || EPI == EPI_BIAS_ADDB_F32)
                bv = bias[gn];
#pragma unroll
            for (int r = 0; r < 4; ++r) {
                size_t off = (size_t)(gmb + r) * ldc + gn;
                float v = acc[i][j][r] + bv;
                if (EPI == EPI_BIAS_ADDB_F32) v += b2f(addp16[off]);
                if (EPI == EPI_ADD_F32)       v += ((const float*)Cout)[off];
                if (EPI == EPI_BIAS_RELU_BF16) v = fmaxf(v, 0.f);
                if (EPI == EPI_BF16 || EPI == EPI_BIAS_BF16 || EPI == EPI_BIAS_RELU_BF16)
                    ((u16*)Cout)[off] = f2b(v);
                else
                    ((float*)Cout)[off] = v;
            }
        }
    }
}

// ---------------- LayerNorm bf16 -> bf16 (may be in-place) ----------------
__global__ void ln_bf16_k(const u16* __restrict__ src, u16* __restrict__ dst,
                          const float* __restrict__ g, const float* __restrict__ be) {
    __shared__ float red[8];
    const int t = blockIdx.x, tid = threadIdx.x;
    ushort4 h = ((const ushort4*)(src + (size_t)t * DD))[tid];
    float4 v = { b2f(h.x), b2f(h.y), b2f(h.z), b2f(h.w) };
    float s  = v.x + v.y + v.z + v.w;
    float ss = v.x * v.x + v.y * v.y + v.z * v.z + v.w * v.w;
    block_red2(s, ss, red, tid);
    float mean = s * (1.f / 1024.f);
    float inv  = 1.0f / sqrtf(ss * (1.f / 1024.f) - mean * mean + 1e-5f);
    float4 gv = ((const float4*)g)[tid];
    float4 bv = ((const float4*)be)[tid];
    ushort4 o;
    o.x = f2b((v.x - mean) * inv * gv.x + bv.x);
    o.y = f2b((v.y - mean) * inv * gv.y + bv.y);
    o.z = f2b((v.z - mean) * inv * gv.z + bv.z);
    o.w = f2b((v.w - mean) * inv * gv.w + bv.w);
    ((ushort4*)(dst + (size_t)t * DD))[tid] = o;
}

// ---------------- final LN in place on d_out (f32) ----------------
__global__ void ln_out_k(float* __restrict__ io, const float* __restrict__ g,
                         const float* __restrict__ be) {
    __shared__ float red[8];
    const int t = blockIdx.x, tid = threadIdx.x;
    float4 v = ((const float4*)(io + (size_t)t * DD))[tid];
    float s  = v.x + v.y + v.z + v.w;
    float ss = v.x * v.x + v.y * v.y + v.z * v.z + v.w * v.w;
    block_red2(s, ss, red, tid);
    float mean = s * (1.f / 1024.f);
    float inv  = 1.0f / sqrtf(ss * (1.f / 1024.f) - mean * mean + 1e-5f);
    float4 gv = ((const float4*)g)[tid];
    float4 bv = ((const float4*)be)[tid];
    float4 o;
    o.x = (v.x - mean) * inv * gv.x + bv.x;
    o.y = (v.y - mean) * inv * gv.y + bv.y;
    o.z = (v.z - mean) * inv * gv.z + bv.z;
    o.w = (v.w - mean) * inv * gv.w + bv.w;
    ((float4*)(io + (size_t)t * DD))[tid] = o;
}

// ---------------- pw1: Sf[b] += Kf .* Xf  (packed spectra) ----------------
#define PW1_TOK 16
__global__ void pw1_k(const u16* __restrict__ FTx, const u16* __restrict__ FTk,
                      float* __restrict__ Sf) {
    const int tid = threadIdx.x;
    const int t0 = blockIdx.x * PW1_TOK;
    const int b = t0 >> 12;
    float a0 = 0.f;
    float ar1 = 0.f, ai1 = 0.f;
    float ar2 = 0.f, ai2 = 0.f;
    const int f1 = tid + 1, f2 = tid + 257;
    for (int it = 0; it < PW1_TOK; ++it) {
        const size_t ro = (size_t)(t0 + it) * DD;
        const u16* rx = FTx + ro;
        const u16* rk = FTk + ro;
        if (tid == 0) a0 += b2f(rk[0]) * b2f(rx[0]);
        {
            float xr = b2f(rx[2 * f1 - 1]), xi = b2f(rx[2 * f1]);
            float kr = b2f(rk[2 * f1 - 1]), ki = b2f(rk[2 * f1]);
            ar1 += kr * xr - ki * xi;
            ai1 += kr * xi + ki * xr;
        }
        if (f2 < 512) {
            float xr = b2f(rx[2 * f2 - 1]), xi = b2f(rx[2 * f2]);
            float kr = b2f(rk[2 * f2 - 1]), ki = b2f(rk[2 * f2]);
            ar2 += kr * xr - ki * xi;
            ai2 += kr * xi + ki * xr;
        } else {
            ar2 += b2f(rk[1023]) * b2f(rx[1023]);
        }
    }
    float* sb = Sf + (size_t)b * DD;
    if (tid == 0) atomicAdd(&sb[0], a0);
    atomicAdd(&sb[2 * f1 - 1], ar1);
    atomicAdd(&sb[2 * f1],     ai1);
    if (f2 < 512) {
        atomicAdd(&sb[2 * f2 - 1], ar2);
        atomicAdd(&sb[2 * f2],     ai2);
    } else {
        atomicAdd(&sb[1023], ar2);
    }
}

// ---------------- pw2: G = Xf + Kf.*Xf + Sf.*conj(Qf), in-place over FTx ----------------
__global__ void pw2_k(u16* __restrict__ FTx, const u16* __restrict__ FTk,
                      const u16* __restrict__ FTq, const float* __restrict__ Sf) {
    const int t = blockIdx.x, tid = threadIdx.x;
    const int b = t >> 12;
    const size_t ro = (size_t)t * DD;
    u16* rx = FTx + ro;
    const u16* rk = FTk + ro;
    const u16* rq = FTq + ro;
    const float* sb = Sf + (size_t)b * DD;
    const int f1 = tid + 1, f2 = tid + 257;
    if (tid == 0) {
        float x = b2f(rx[0]), k = b2f(rk[0]), q = b2f(rq[0]);
        rx[0] = f2b(x + k * x + sb[0] * q);
    }
    {
        float xr = b2f(rx[2 * f1 - 1]), xi = b2f(rx[2 * f1]);
        float kr = b2f(rk[2 * f1 - 1]), ki = b2f(rk[2 * f1]);
        float qr = b2f(rq[2 * f1 - 1]), qi = b2f(rq[2 * f1]);
        float sr = sb[2 * f1 - 1], si = sb[2 * f1];
        rx[2 * f1 - 1] = f2b(xr + (kr * xr - ki * xi) + (sr * qr + si * qi));
        rx[2 * f1]     = f2b(xi + (kr * xi + ki * xr) + (si * qr - sr * qi));
    }
    if (f2 < 512) {
        float xr = b2f(rx[2 * f2 - 1]), xi = b2f(rx[2 * f2]);
        float kr = b2f(rk[2 * f2 - 1]), ki = b2f(rk[2 * f2]);
        float qr = b2f(rq[2 * f2 - 1]), qi = b2f(rq[2 * f2]);
        float sr = sb[2 * f2 - 1], si = sb[2 * f2];
        rx[2 * f2 - 1] = f2b(xr + (kr * xr - ki * xi) + (sr * qr + si * qi));
        rx[2 * f2]     = f2b(xi + (kr * xi + ki * xr) + (si * qr - sr * qi));
    } else {
        float x = b2f(rx[1023]), k = b2f(rk[1023]), q = b2f(rq[1023]);
        rx[1023] = f2b(x + k * x + sb[1023] * q);
    }
}

// ---------------- launch ----------------
extern "C" void kernel_launch(void* const* d_in, const int* in_sizes, int n_in,
                              void* d_out, int out_size, void* d_ws, size_t ws_size,
                              hipStream_t stream) {
    const float* x     = (const float*)d_in[0];
    const float* Wq    = (const float*)d_in[1];
    const float* bq    = (const float*)d_in[2];
    const float* gq    = (const float*)d_in[3];
    const float* betaq = (const float*)d_in[4];
    const float* Wk    = (const float*)d_in[5];
    const float* bk    = (const float*)d_in[6];
    const float* gk    = (const float*)d_in[7];
    const float* betak = (const float*)d_in[8];
    const float* g0    = (const float*)d_in[9];
    const float* beta0 = (const float*)d_in[10];
    const float* W1    = (const float*)d_in[11];
    const float* b1    = (const float*)d_in[12];
    const float* W2    = (const float*)d_in[13];
    const float* b2    = (const float*)d_in[14];
    const float* g1    = (const float*)d_in[15];
    const float* beta1 = (const float*)d_in[16];

    char* ws = (char*)d_ws;
    u16* S1 = (u16*)(ws + S1O);   // xb16 -> FTk -> x1b
    u16* S2 = (u16*)(ws + S2O);   // qb -> T
    u16* S3 = (u16*)(ws + S3O);   // kb -> FTq -> H chunk
    u16* S4 = (u16*)(ws + S4O);   // FTx -> G -> H chunk
    u16* wq16 = (u16*)(ws + O_WQ);
    u16* wk16 = (u16*)(ws + O_WK);
    u16* w116 = (u16*)(ws + O_W1);
    u16* w216 = (u16*)(ws + O_W2);
    u16* fwdP = (u16*)(ws + O_FWD);
    u16* invP = (u16*)(ws + O_INV);
    float* Sf = (float*)(ws + O_SF);
    float* out = (float*)d_out;

    // consts
    zero_sf_k<<<16, 256, 0, stream>>>(Sf);
    cast_f32_bf16_k<<<16384, 256, 0, stream>>>(x, S1, 4194304);
    cast_f32_bf16_k<<<1024, 256, 0, stream>>>(Wq, wq16, 262144);
    cast_f32_bf16_k<<<1024, 256, 0, stream>>>(Wk, wk16, 262144);
    cast_f32_bf16_k<<<4096, 256, 0, stream>>>(W1, w116, 1048576);
    cast_f32_bf16_k<<<4096, 256, 0, stream>>>(W2, w216, 1048576);
    gen_fwd_k<<<4096, 256, 0, stream>>>(fwdP);
    gen_inv_k<<<4096, 256, 0, stream>>>(invP);

    // projections (bias in epilogue, bf16 out), then LN in-place
    gemm_bt_k<EPI_BIAS_BF16><<<dim3(8, 128), 256, 0, stream>>>(S1, wq16, S2, bq, nullptr, 1024, 1024, 1024, 1024);
    gemm_bt_k<EPI_BIAS_BF16><<<dim3(8, 128), 256, 0, stream>>>(S1, wk16, S3, bk, nullptr, 1024, 1024, 1024, 1024);
    ln_bf16_k<<<NT, 256, 0, stream>>>(S2, S2, gq, betaq);
    ln_bf16_k<<<NT, 256, 0, stream>>>(S3, S3, gk, betak);

    // forward DFTs (packed spectra)
    gemm_bt_k<EPI_BF16><<<dim3(8, 128), 256, 0, stream>>>(S1, fwdP, S4, nullptr, nullptr, 1024, 1024, 1024, 1024); // FTx
    gemm_bt_k<EPI_BF16><<<dim3(8, 128), 256, 0, stream>>>(S3, fwdP, S1, nullptr, nullptr, 1024, 1024, 1024, 1024); // FTk
    gemm_bt_k<EPI_BF16><<<dim3(8, 128), 256, 0, stream>>>(S2, fwdP, S3, nullptr, nullptr, 1024, 1024, 1024, 1024); // FTq

    // freq-domain pointwise
    pw1_k<<<NT / PW1_TOK, 256, 0, stream>>>(S4, S1, Sf);
    pw2_k<<<NT, 256, 0, stream>>>(S4, S1, S3, Sf);   // G in-place over FTx (S4)

    // inverse DFT: T = G @ Inv^T (bf16)
    gemm_bt_k<EPI_BF16><<<dim3(8, 128), 256, 0, stream>>>(S4, invP, S2, nullptr, nullptr, 1024, 1024, 1024, 1024);

    // x1 = LN(T) -> bf16
    ln_bf16_k<<<NT, 256, 0, stream>>>(S2, S1, g0, beta0);

    // FFN in two F-chunks of 2048; H chunk lives in S3..S4 (64MB)
    gemm_bt_k<EPI_BIAS_RELU_BF16><<<dim3(16, 128), 256, 0, stream>>>(S1, w116, S3, b1, nullptr, 1024, 1024, 1024, 2048);
    gemm_bt_k<EPI_BIAS_ADDB_F32><<<dim3(8, 128), 256, 0, stream>>>(S3, w216, out, b2, S1, 2048, 2048, 4096, 1024);
    gemm_bt_k<EPI_BIAS_RELU_BF16><<<dim3(16, 128), 256, 0, stream>>>(S1, w116 + (size_t)2048 * 1024, S3, b1 + 2048, nullptr, 1024, 1024, 1024, 2048);
    gemm_bt_k<EPI_ADD_F32><<<dim3(8, 128), 256, 0, stream>>>(S3, w216 + 2048, out, nullptr, nullptr, 2048, 2048, 4096, 1024);

    // final LN in place
    ln_out_k<<<NT, 256, 0, stream>>>(out, g1, beta1);

    (void)in_sizes; (void)n_in; (void)out_size; (void)ws_size;
}

// Round 5
// 787.821 us; speedup vs baseline: 1.3433x; 1.2583x over previous
//
#include <hip/hip_runtime.h>

typedef unsigned short u16;
typedef unsigned int   u32;
typedef __attribute__((ext_vector_type(8))) __bf16 bf16x8;
typedef __attribute__((ext_vector_type(4))) float   f32x4;

// ---------------- dims ----------------
#define NT   16384      // tokens = 4*4096
#define DD   1024
#define FFD  4096

// ---------------- ws layout (bytes), total ~152 MB ----------------
#define SREG  ((size_t)33554432)            // 32MB = 16384*1024*2
#define S1O   ((size_t)0)
#define S2O   (SREG)
#define S3O   (2*SREG)
#define S4O   (3*SREG)
#define O_WQ  (4*SREG)                      // 134,217,728
#define O_WK  (O_WQ + (size_t)2097152)
#define O_W1  (O_WK + (size_t)2097152)
#define O_W2  (O_W1 + (size_t)8388608)
#define O_FWD (O_W2 + (size_t)8388608)
#define O_INV (O_FWD + (size_t)2097152)
#define O_SF  (O_INV + (size_t)2097152)
// end = O_SF + 16384 = 159,399,936 bytes

// ---------------- helpers ----------------
__device__ __forceinline__ float b2f(u16 h) {
    u32 u = ((u32)h) << 16;
    return __uint_as_float(u);
}
__device__ __forceinline__ u16 f2b(float f) {  // RNE
    u32 u = __float_as_uint(f);
    u32 r = (u + 0x7FFFu + ((u >> 16) & 1u)) >> 16;
    return (u16)r;
}

__device__ __forceinline__ void ld16(const u16* g, u16* l) {
    __builtin_amdgcn_global_load_lds(
        (const __attribute__((address_space(1))) void*)g,
        (__attribute__((address_space(3))) void*)l, 16, 0, 0);
}

__device__ __forceinline__ void block_red2(float& a, float& b, float* red, int tid) {
#pragma unroll
    for (int off = 32; off; off >>= 1) {
        a += __shfl_down(a, off, 64);
        b += __shfl_down(b, off, 64);
    }
    int w = tid >> 6;
    if ((tid & 63) == 0) { red[w] = a; red[4 + w] = b; }
    __syncthreads();
    a = red[0] + red[1] + red[2] + red[3];
    b = red[4] + red[5] + red[6] + red[7];
}

// ---------------- small utility kernels ----------------
__global__ void zero_sf_k(float* __restrict__ Sf) {
    int i = blockIdx.x * 256 + threadIdx.x;
    if (i < 4096) Sf[i] = 0.f;
}

__global__ void cast_f32_bf16_k(const float* __restrict__ s, u16* __restrict__ d, int n4) {
    int i = blockIdx.x * 256 + threadIdx.x;
    if (i < n4) {
        float4 v = ((const float4*)s)[i];
        ushort4 o;
        o.x = f2b(v.x); o.y = f2b(v.y); o.z = f2b(v.z); o.w = f2b(v.w);
        ((ushort4*)d)[i] = o;
    }
}

// ---------------- packed-spectrum DFT matrices (bf16) ----------------
// Packed layout (1024 cols): col0 = Re F_0; odd n -> Re F_{(n+1)/2}; even n>0 -> Im F_{n/2};
// col 1023 (odd) -> Re F_512.  numpy rfft: F_f = sum_k v_k e^{-2pi i f k /1024}.
__global__ void gen_fwd_k(u16* __restrict__ Fwd) {
    int idx = blockIdx.x * 256 + threadIdx.x;   // 1024*1024
    int n = idx >> 10, k = idx & 1023;
    int f  = (n == 0) ? 0 : ((n & 1) ? ((n + 1) >> 1) : (n >> 1));
    bool re = (n == 0) || (n & 1);
    int r = (f * k) & 1023;
    float ang = (float)r * 6.1359233e-3f;   // 2*pi/1024
    float v = re ? __cosf(ang) : -__sinf(ang);
    Fwd[idx] = f2b(v);
}
// irfft: v_d = (1/1024)[F_0 + (-1)^d Re F_512 + 2*sum_{f=1}^{511}(Re F_f cos - Im F_f sin)]
__global__ void gen_inv_k(u16* __restrict__ Inv) {
    int idx = blockIdx.x * 256 + threadIdx.x;   // 1024*1024
    int d = idx >> 10, n = idx & 1023;
    int f  = (n == 0) ? 0 : ((n & 1) ? ((n + 1) >> 1) : (n >> 1));
    bool re = (n == 0) || (n & 1);
    int r = (f * d) & 1023;
    float ang = (float)r * 6.1359233e-3f;
    float c = (f == 0 || f == 512) ? (1.0f / 1024.0f) : (2.0f / 1024.0f);
    float v = re ? c * __cosf(ang) : -c * __sinf(ang);
    Inv[idx] = f2b(v);
}

// ---------------- GEMM: C[m,n] = sum_k A[m,k]*B[n,k] ----------------
// m97 structure + XCD swizzle + XOR-swizzled LDS (bank-conflict-free, staged
// by permuting each lane's GLOBAL chunk so global_load_lds's fixed lane->slot
// mapping still lands contiguously; slot (r,c) holds global chunk c^(r&7)).
#define BM 128
#define BN 128
#define BK 64
#define EPI_BF16            0  // bf16 store
#define EPI_BIAS_BF16       1  // bf16 store, + bias[n]
#define EPI_BIAS_RELU_BF16  2  // bf16 store, + bias[n], relu
#define EPI_BIAS_ADDB_F32   3  // f32 store,  + bias[n] + bf16 residual addp16[off]
#define EPI_ADD_F32         4  // f32 store,  + existing f32 Cout[off]

template <int EPI>
__global__ __launch_bounds__(256, 3) void gemm_bt_k(
    const u16* __restrict__ A, const u16* __restrict__ B, void* __restrict__ Cout,
    const float* __restrict__ bias, const u16* __restrict__ addp16,
    int K, int lda, int ldb, int ldc)
{
    __shared__ __align__(16) u16 As[BM * BK];
    __shared__ __align__(16) u16 Bs[BN * BK];
    const int tid = threadIdx.x;

    // XCD-aware swizzle: blocks with id%8==c (one XCD) cover a CONTIGUOUS
    // m-band x all n-tiles -> per-XCD A footprint drops 8x.
    int m0, n0;
    {
        const int id = blockIdx.y * gridDim.x + blockIdx.x;
        const int nb = gridDim.x * gridDim.y;
        if ((nb & 7) == 0) {
            const int per = nb >> 3;
            const int t = (id & 7) * per + (id >> 3);
            n0 = (t % gridDim.x) * BN;
            m0 = (t / gridDim.x) * BM;
        } else {
            n0 = blockIdx.x * BN;
            m0 = blockIdx.y * BM;
        }
    }

    const int w = tid >> 6, l = tid & 63;
    const int wm = (w >> 1) << 6, wn = (w & 1) << 6;
    const int tm = l & 15, quad = l >> 4;
    const int sw = (tm & 7) << 3;            // read-side XOR swizzle (in u16 elems)

    f32x4 acc[4][4] = {};

    const int sr = tid >> 3;
    const int sc = ((tid & 7) ^ (sr & 7)) << 3;   // staged-side swizzled global chunk
    const u16* Ag = A + (size_t)(m0 + sr) * lda;
    const u16* Bg = B + (size_t)(n0 + sr) * ldb;
    u16* Asl = As + tid * 8;
    u16* Bsl = Bs + tid * 8;
    const size_t a32 = (size_t)32 * lda, b32 = (size_t)32 * ldb;

    for (int k0 = 0; k0 < K; k0 += BK) {
#pragma unroll
        for (int i = 0; i < 4; ++i) {
            ld16(Ag + (size_t)i * a32 + k0 + sc, Asl + i * 2048);
            ld16(Bg + (size_t)i * b32 + k0 + sc, Bsl + i * 2048);
        }
        __syncthreads();
#pragma unroll
        for (int kk = 0; kk < BK; kk += 32) {
            bf16x8 af[4], bfr[4];
#pragma unroll
            for (int i = 0; i < 4; ++i)
                af[i] = *(const bf16x8*)(const void*)(As + (wm + i * 16 + tm) * BK + ((((kk >> 3) + quad) << 3) ^ sw));
#pragma unroll
            for (int j = 0; j < 4; ++j)
                bfr[j] = *(const bf16x8*)(const void*)(Bs + (wn + j * 16 + tm) * BK + ((((kk >> 3) + quad) << 3) ^ sw));
#pragma unroll
            for (int i = 0; i < 4; ++i)
#pragma unroll
                for (int j = 0; j < 4; ++j)
                    acc[i][j] = __builtin_amdgcn_mfma_f32_16x16x32_bf16(af[i], bfr[j], acc[i][j], 0, 0, 0);
        }
        __syncthreads();
    }

    // C/D layout: col=lane&15, row=quad*4+reg (m89/m91-verified)
#pragma unroll
    for (int i = 0; i < 4; ++i) {
        const int gmb = m0 + wm + i * 16 + quad * 4;
#pragma unroll
        for (int j = 0; j < 4; ++j) {
            const int gn = n0 + wn + j * 16 + tm;
            float bv = 0.f;
            if (EPI == EPI_BIAS_BF16 || EPI == EPI_BIAS_RELU_BF16 || EPI == EPI_BIAS_ADDB_F32)
                bv = bias[gn];
#pragma unroll
            for (int r = 0; r < 4; ++r) {
                size_t off = (size_t)(gmb + r) * ldc + gn;
                float v = acc[i][j][r] + bv;
                if (EPI == EPI_BIAS_ADDB_F32) v += b2f(addp16[off]);
                if (EPI == EPI_ADD_F32)       v += ((const float*)Cout)[off];
                if (EPI == EPI_BIAS_RELU_BF16) v = fmaxf(v, 0.f);
                if (EPI == EPI_BF16 || EPI == EPI_BIAS_BF16 || EPI == EPI_BIAS_RELU_BF16)
                    ((u16*)Cout)[off] = f2b(v);
                else
                    ((float*)Cout)[off] = v;
            }
        }
    }
}

// ---------------- LayerNorm bf16 -> bf16 (may be in-place) ----------------
__global__ void ln_bf16_k(const u16* __restrict__ src, u16* __restrict__ dst,
                          const float* __restrict__ g, const float* __restrict__ be) {
    __shared__ float red[8];
    const int t = blockIdx.x, tid = threadIdx.x;
    ushort4 h = ((const ushort4*)(src + (size_t)t * DD))[tid];
    float4 v = { b2f(h.x), b2f(h.y), b2f(h.z), b2f(h.w) };
    float s  = v.x + v.y + v.z + v.w;
    float ss = v.x * v.x + v.y * v.y + v.z * v.z + v.w * v.w;
    block_red2(s, ss, red, tid);
    float mean = s * (1.f / 1024.f);
    float inv  = 1.0f / sqrtf(ss * (1.f / 1024.f) - mean * mean + 1e-5f);
    float4 gv = ((const float4*)g)[tid];
    float4 bv = ((const float4*)be)[tid];
    ushort4 o;
    o.x = f2b((v.x - mean) * inv * gv.x + bv.x);
    o.y = f2b((v.y - mean) * inv * gv.y + bv.y);
    o.z = f2b((v.z - mean) * inv * gv.z + bv.z);
    o.w = f2b((v.w - mean) * inv * gv.w + bv.w);
    ((ushort4*)(dst + (size_t)t * DD))[tid] = o;
}

// ---------------- final LN in place on d_out (f32) ----------------
__global__ void ln_out_k(float* __restrict__ io, const float* __restrict__ g,
                         const float* __restrict__ be) {
    __shared__ float red[8];
    const int t = blockIdx.x, tid = threadIdx.x;
    float4 v = ((const float4*)(io + (size_t)t * DD))[tid];
    float s  = v.x + v.y + v.z + v.w;
    float ss = v.x * v.x + v.y * v.y + v.z * v.z + v.w * v.w;
    block_red2(s, ss, red, tid);
    float mean = s * (1.f / 1024.f);
    float inv  = 1.0f / sqrtf(ss * (1.f / 1024.f) - mean * mean + 1e-5f);
    float4 gv = ((const float4*)g)[tid];
    float4 bv = ((const float4*)be)[tid];
    float4 o;
    o.x = (v.x - mean) * inv * gv.x + bv.x;
    o.y = (v.y - mean) * inv * gv.y + bv.y;
    o.z = (v.z - mean) * inv * gv.z + bv.z;
    o.w = (v.w - mean) * inv * gv.w + bv.w;
    ((float4*)(io + (size_t)t * DD))[tid] = o;
}

// ---------------- pw1: Sf[b] += Kf .* Xf  (packed spectra) ----------------
#define PW1_TOK 16
__global__ void pw1_k(const u16* __restrict__ FTx, const u16* __restrict__ FTk,
                      float* __restrict__ Sf) {
    const int tid = threadIdx.x;
    const int t0 = blockIdx.x * PW1_TOK;
    const int b = t0 >> 12;
    float a0 = 0.f;
    float ar1 = 0.f, ai1 = 0.f;
    float ar2 = 0.f, ai2 = 0.f;
    const int f1 = tid + 1, f2 = tid + 257;
    for (int it = 0; it < PW1_TOK; ++it) {
        const size_t ro = (size_t)(t0 + it) * DD;
        const u16* rx = FTx + ro;
        const u16* rk = FTk + ro;
        if (tid == 0) a0 += b2f(rk[0]) * b2f(rx[0]);
        {
            float xr = b2f(rx[2 * f1 - 1]), xi = b2f(rx[2 * f1]);
            float kr = b2f(rk[2 * f1 - 1]), ki = b2f(rk[2 * f1]);
            ar1 += kr * xr - ki * xi;
            ai1 += kr * xi + ki * xr;
        }
        if (f2 < 512) {
            float xr = b2f(rx[2 * f2 - 1]), xi = b2f(rx[2 * f2]);
            float kr = b2f(rk[2 * f2 - 1]), ki = b2f(rk[2 * f2]);
            ar2 += kr * xr - ki * xi;
            ai2 += kr * xi + ki * xr;
        } else {
            ar2 += b2f(rk[1023]) * b2f(rx[1023]);
        }
    }
    float* sb = Sf + (size_t)b * DD;
    if (tid == 0) atomicAdd(&sb[0], a0);
    atomicAdd(&sb[2 * f1 - 1], ar1);
    atomicAdd(&sb[2 * f1],     ai1);
    if (f2 < 512) {
        atomicAdd(&sb[2 * f2 - 1], ar2);
        atomicAdd(&sb[2 * f2],     ai2);
    } else {
        atomicAdd(&sb[1023], ar2);
    }
}

// ---------------- pw2: G = Xf + Kf.*Xf + Sf.*conj(Qf), in-place over FTx ----------------
__global__ void pw2_k(u16* __restrict__ FTx, const u16* __restrict__ FTk,
                      const u16* __restrict__ FTq, const float* __restrict__ Sf) {
    const int t = blockIdx.x, tid = threadIdx.x;
    const int b = t >> 12;
    const size_t ro = (size_t)t * DD;
    u16* rx = FTx + ro;
    const u16* rk = FTk + ro;
    const u16* rq = FTq + ro;
    const float* sb = Sf + (size_t)b * DD;
    const int f1 = tid + 1, f2 = tid + 257;
    if (tid == 0) {
        float x = b2f(rx[0]), k = b2f(rk[0]), q = b2f(rq[0]);
        rx[0] = f2b(x + k * x + sb[0] * q);
    }
    {
        float xr = b2f(rx[2 * f1 - 1]), xi = b2f(rx[2 * f1]);
        float kr = b2f(rk[2 * f1 - 1]), ki = b2f(rk[2 * f1]);
        float qr = b2f(rq[2 * f1 - 1]), qi = b2f(rq[2 * f1]);
        float sr = sb[2 * f1 - 1], si = sb[2 * f1];
        rx[2 * f1 - 1] = f2b(xr + (kr * xr - ki * xi) + (sr * qr + si * qi));
        rx[2 * f1]     = f2b(xi + (kr * xi + ki * xr) + (si * qr - sr * qi));
    }
    if (f2 < 512) {
        float xr = b2f(rx[2 * f2 - 1]), xi = b2f(rx[2 * f2]);
        float kr = b2f(rk[2 * f2 - 1]), ki = b2f(rk[2 * f2]);
        float qr = b2f(rq[2 * f2 - 1]), qi = b2f(rq[2 * f2]);
        float sr = sb[2 * f2 - 1], si = sb[2 * f2];
        rx[2 * f2 - 1] = f2b(xr + (kr * xr - ki * xi) + (sr * qr + si * qi));
        rx[2 * f2]     = f2b(xi + (kr * xi + ki * xr) + (si * qr - sr * qi));
    } else {
        float x = b2f(rx[1023]), k = b2f(rk[1023]), q = b2f(rq[1023]);
        rx[1023] = f2b(x + k * x + sb[1023] * q);
    }
}

// ---------------- launch ----------------
extern "C" void kernel_launch(void* const* d_in, const int* in_sizes, int n_in,
                              void* d_out, int out_size, void* d_ws, size_t ws_size,
                              hipStream_t stream) {
    const float* x     = (const float*)d_in[0];
    const float* Wq    = (const float*)d_in[1];
    const float* bq    = (const float*)d_in[2];
    const float* gq    = (const float*)d_in[3];
    const float* betaq = (const float*)d_in[4];
    const float* Wk    = (const float*)d_in[5];
    const float* bk    = (const float*)d_in[6];
    const float* gk    = (const float*)d_in[7];
    const float* betak = (const float*)d_in[8];
    const float* g0    = (const float*)d_in[9];
    const float* beta0 = (const float*)d_in[10];
    const float* W1    = (const float*)d_in[11];
    const float* b1    = (const float*)d_in[12];
    const float* W2    = (const float*)d_in[13];
    const float* b2    = (const float*)d_in[14];
    const float* g1    = (const float*)d_in[15];
    const float* beta1 = (const float*)d_in[16];

    char* ws = (char*)d_ws;
    u16* S1 = (u16*)(ws + S1O);   // xb16 -> FTk -> x1b
    u16* S2 = (u16*)(ws + S2O);   // qb -> T
    u16* S3 = (u16*)(ws + S3O);   // kb -> FTq -> H chunk
    u16* S4 = (u16*)(ws + S4O);   // FTx -> G -> H chunk
    u16* wq16 = (u16*)(ws + O_WQ);
    u16* wk16 = (u16*)(ws + O_WK);
    u16* w116 = (u16*)(ws + O_W1);
    u16* w216 = (u16*)(ws + O_W2);
    u16* fwdP = (u16*)(ws + O_FWD);
    u16* invP = (u16*)(ws + O_INV);
    float* Sf = (float*)(ws + O_SF);
    float* out = (float*)d_out;

    // consts
    zero_sf_k<<<16, 256, 0, stream>>>(Sf);
    cast_f32_bf16_k<<<16384, 256, 0, stream>>>(x, S1, 4194304);
    cast_f32_bf16_k<<<1024, 256, 0, stream>>>(Wq, wq16, 262144);
    cast_f32_bf16_k<<<1024, 256, 0, stream>>>(Wk, wk16, 262144);
    cast_f32_bf16_k<<<4096, 256, 0, stream>>>(W1, w116, 1048576);
    cast_f32_bf16_k<<<4096, 256, 0, stream>>>(W2, w216, 1048576);
    gen_fwd_k<<<4096, 256, 0, stream>>>(fwdP);
    gen_inv_k<<<4096, 256, 0, stream>>>(invP);

    // projections (bias in epilogue, bf16 out), then LN in-place
    gemm_bt_k<EPI_BIAS_BF16><<<dim3(8, 128), 256, 0, stream>>>(S1, wq16, S2, bq, nullptr, 1024, 1024, 1024, 1024);
    gemm_bt_k<EPI_BIAS_BF16><<<dim3(8, 128), 256, 0, stream>>>(S1, wk16, S3, bk, nullptr, 1024, 1024, 1024, 1024);
    ln_bf16_k<<<NT, 256, 0, stream>>>(S2, S2, gq, betaq);
    ln_bf16_k<<<NT, 256, 0, stream>>>(S3, S3, gk, betak);

    // forward DFTs (packed spectra)
    gemm_bt_k<EPI_BF16><<<dim3(8, 128), 256, 0, stream>>>(S1, fwdP, S4, nullptr, nullptr, 1024, 1024, 1024, 1024); // FTx
    gemm_bt_k<EPI_BF16><<<dim3(8, 128), 256, 0, stream>>>(S3, fwdP, S1, nullptr, nullptr, 1024, 1024, 1024, 1024); // FTk
    gemm_bt_k<EPI_BF16><<<dim3(8, 128), 256, 0, stream>>>(S2, fwdP, S3, nullptr, nullptr, 1024, 1024, 1024, 1024); // FTq

    // freq-domain pointwise
    pw1_k<<<NT / PW1_TOK, 256, 0, stream>>>(S4, S1, Sf);
    pw2_k<<<NT, 256, 0, stream>>>(S4, S1, S3, Sf);   // G in-place over FTx (S4)

    // inverse DFT: T = G @ Inv^T (bf16)
    gemm_bt_k<EPI_BF16><<<dim3(8, 128), 256, 0, stream>>>(S4, invP, S2, nullptr, nullptr, 1024, 1024, 1024, 1024);

    // x1 = LN(T) -> bf16
    ln_bf16_k<<<NT, 256, 0, stream>>>(S2, S1, g0, beta0);

    // FFN in two F-chunks of 2048; H chunk lives in S3..S4 (64MB)
    gemm_bt_k<EPI_BIAS_RELU_BF16><<<dim3(16, 128), 256, 0, stream>>>(S1, w116, S3, b1, nullptr, 1024, 1024, 1024, 2048);
    gemm_bt_k<EPI_BIAS_ADDB_F32><<<dim3(8, 128), 256, 0, stream>>>(S3, w216, out, b2, S1, 2048, 2048, 4096, 1024);
    gemm_bt_k<EPI_BIAS_RELU_BF16><<<dim3(16, 128), 256, 0, stream>>>(S1, w116 + (size_t)2048 * 1024, S3, b1 + 2048, nullptr, 1024, 1024, 1024, 2048);
    gemm_bt_k<EPI_ADD_F32><<<dim3(8, 128), 256, 0, stream>>>(S3, w216 + 2048, out, nullptr, nullptr, 2048, 2048, 4096, 1024);

    // final LN in place
    ln_out_k<<<NT, 256, 0, stream>>>(out, g1, beta1);

    (void)in_sizes; (void)n_in; (void)out_size; (void)ws_size;
}